// Round 7
// baseline (956.135 us; speedup 1.0000x reference)
//
#include <hip/hip_runtime.h>
#include <hip/hip_bf16.h>
#include <stdint.h>

#define S_DIM 2048
#define D_DIM 128
#define QBLK 256          // 8 waves x 32 q-rows
#define KVBLK 64

typedef __attribute__((ext_vector_type(8)))  __bf16 bf16x8;
typedef __attribute__((ext_vector_type(16))) float  f32x16;
typedef __attribute__((ext_vector_type(2)))  unsigned int u32x2;
typedef __attribute__((ext_vector_type(4)))  unsigned int u32x4;

__device__ __forceinline__ uint32_t lds_off(const void* p) {
    return (uint32_t)(uintptr_t)p;   // low 32 bits of LDS flat addr = byte offset
}
__device__ __forceinline__ uint32_t pk2(float lo, float hi) {
    unsigned short a = __builtin_bit_cast(unsigned short, (__bf16)lo);
    unsigned short b = __builtin_bit_cast(unsigned short, (__bf16)hi);
    return (uint32_t)a | ((uint32_t)b << 16);
}

struct StageRegs { float4 k0, k1, k2, k3, v0, v1, v2, v3; };

// V window layout: elem idx = 72*W + (d&15) + 16*(kv&3)  [144 B windows]
//   W = 2*(d>>5) + ((d>>4)&1) + 8*((kv>>2)&1) + 16*((kv>>3)&1) + 32*(kv>>4)
#define TRSET(p0,p1,p2,p3,p4,p5,p6,p7, A) \
  asm volatile("ds_read_b64_tr_b16 %0, %1"              : "=v"(p0) : "v"(A)); \
  asm volatile("ds_read_b64_tr_b16 %0, %1 offset:1152"  : "=v"(p1) : "v"(A)); \
  asm volatile("ds_read_b64_tr_b16 %0, %1 offset:4608"  : "=v"(p2) : "v"(A)); \
  asm volatile("ds_read_b64_tr_b16 %0, %1 offset:5760"  : "=v"(p3) : "v"(A)); \
  asm volatile("ds_read_b64_tr_b16 %0, %1 offset:9216"  : "=v"(p4) : "v"(A)); \
  asm volatile("ds_read_b64_tr_b16 %0, %1 offset:10368" : "=v"(p5) : "v"(A)); \
  asm volatile("ds_read_b64_tr_b16 %0, %1 offset:13824" : "=v"(p6) : "v"(A)); \
  asm volatile("ds_read_b64_tr_b16 %0, %1 offset:14976" : "=v"(p7) : "v"(A));

#define MFMA4(nb, q0,q1,q2,q3,q4,q5,q6,q7)                                          \
  { u32x4 bu0 = {q0[0], q0[1], q1[0], q1[1]};                                       \
    o[nb] = __builtin_amdgcn_mfma_f32_32x32x16_bf16(                                \
        __builtin_bit_cast(bf16x8, pa0), __builtin_bit_cast(bf16x8, bu0), o[nb],0,0,0); \
    u32x4 bu1 = {q2[0], q2[1], q3[0], q3[1]};                                       \
    o[nb] = __builtin_amdgcn_mfma_f32_32x32x16_bf16(                                \
        __builtin_bit_cast(bf16x8, pa1), __builtin_bit_cast(bf16x8, bu1), o[nb],0,0,0); \
    u32x4 bu2 = {q4[0], q4[1], q5[0], q5[1]};                                       \
    o[nb] = __builtin_amdgcn_mfma_f32_32x32x16_bf16(                                \
        __builtin_bit_cast(bf16x8, pa2), __builtin_bit_cast(bf16x8, bu2), o[nb],0,0,0); \
    u32x4 bu3 = {q6[0], q6[1], q7[0], q7[1]};                                       \
    o[nb] = __builtin_amdgcn_mfma_f32_32x32x16_bf16(                                \
        __builtin_bit_cast(bf16x8, pa3), __builtin_bit_cast(bf16x8, bu3), o[nb],0,0,0); }

__global__ __launch_bounds__(512, 4)
void attn_fwd(const float* __restrict__ Q, const float* __restrict__ K,
              const float* __restrict__ V, float* __restrict__ O) {
    __shared__ __bf16 k_lds[2][KVBLK * D_DIM];      // row-major, byte ^= ((row&15)<<4)
    __shared__ __align__(16) char v_lds[2][18432];  // 128 windows x 144 B

    const int tid  = threadIdx.x;
    const int lane = tid & 63;
    const int wv   = tid >> 6;
    const int hi   = lane >> 5;
    const int qcol = lane & 31;

    // ---- block mapping: XCD-pinned by bh, makespan-paired jb ----
    const int bid  = (int)blockIdx.x;            // 0..511
    const int half = bid >> 8;
    const int idx  = bid & 255;
    const int xcd  = idx & 7;
    const int sub  = idx >> 3;
    const int bhg  = sub & 7;
    const int pp   = sub >> 3;
    const int jb   = half ? pp : 7 - pp;         // long blocks dispatch first
    const int bh   = bhg * 8 + xcd;
    const int q0b  = jb * QBLK;
    const int q0w  = q0b + wv * 32;
    const int qg   = q0w + qcol;

    const size_t base = (size_t)bh * S_DIM * D_DIM;
    const float* Qb = Q + base;
    const float* Kb = K + base;
    const float* Vb = V + base;

    // ---- staging: thread -> rows (sr, sr+32), 16B-chunk sc ----
    const int sr = tid >> 4;    // 0..31
    const int sc = tid & 15;    // 0..15
    const float* kg = Kb + (size_t)sr * D_DIM + sc * 8;
    const float* vg = Vb + (size_t)sr * D_DIM + sc * 8;
    const uint32_t kx    = (uint32_t)((sr & 15) << 4);
    const uint32_t koffA = (uint32_t)(sr * 256 + ((sc * 16) ^ kx));
    const uint32_t koffB = (uint32_t)((sr + 32) * 256 + ((sc * 16) ^ kx));
    const uint32_t voffA = (uint32_t)(144 * (2*(sc>>2) + ((sc>>1)&1) + 8*((sr>>2)&1)
                           + 16*((sr>>3)&1) + 32*(sr>>4)) + 16*(sc&1) + 32*(sr&3));
    const uint32_t voffB = voffA + 9216;         // rows +32 -> W += 64

    auto stage_load = [&](StageRegs& R, int t) {
        const size_t off = (size_t)t * KVBLK * D_DIM;
        R.k0 = *reinterpret_cast<const float4*>(kg + off);
        R.k1 = *reinterpret_cast<const float4*>(kg + off + 4);
        R.k2 = *reinterpret_cast<const float4*>(kg + off + 32 * D_DIM);
        R.k3 = *reinterpret_cast<const float4*>(kg + off + 32 * D_DIM + 4);
        R.v0 = *reinterpret_cast<const float4*>(vg + off);
        R.v1 = *reinterpret_cast<const float4*>(vg + off + 4);
        R.v2 = *reinterpret_cast<const float4*>(vg + off + 32 * D_DIM);
        R.v3 = *reinterpret_cast<const float4*>(vg + off + 32 * D_DIM + 4);
    };
    auto cvt8 = [](const float4& a, const float4& b) {
        bf16x8 r;
        r[0]=(__bf16)a.x; r[1]=(__bf16)a.y; r[2]=(__bf16)a.z; r[3]=(__bf16)a.w;
        r[4]=(__bf16)b.x; r[5]=(__bf16)b.y; r[6]=(__bf16)b.z; r[7]=(__bf16)b.w;
        return r;
    };
    auto stage_write = [&](const StageRegs& R, int buf) {
        char* kp = (char*)&k_lds[buf][0];
        *reinterpret_cast<bf16x8*>(kp + koffA) = cvt8(R.k0, R.k1);
        *reinterpret_cast<bf16x8*>(kp + koffB) = cvt8(R.k2, R.k3);
        char* vp = (char*)&v_lds[buf][0];
        *reinterpret_cast<bf16x8*>(vp + voffA) = cvt8(R.v0, R.v1);
        *reinterpret_cast<bf16x8*>(vp + voffB) = cvt8(R.v2, R.v3);
    };

    // ---- Q B-fragments (scale folded) ----
    const float qs = 0.08838834764831845f;
    bf16x8 aq[8];
    #pragma unroll
    for (int ch = 0; ch < 8; ++ch) {
        const float* qp = Qb + (size_t)qg * D_DIM + ch * 16 + hi * 8;
        float4 x = *reinterpret_cast<const float4*>(qp);
        float4 y = *reinterpret_cast<const float4*>(qp + 4);
        bf16x8 r;
        r[0]=(__bf16)(x.x*qs); r[1]=(__bf16)(x.y*qs); r[2]=(__bf16)(x.z*qs); r[3]=(__bf16)(x.w*qs);
        r[4]=(__bf16)(y.x*qs); r[5]=(__bf16)(y.y*qs); r[6]=(__bf16)(y.z*qs); r[7]=(__bf16)(y.w*qs);
        aq[ch] = r;
    }

    f32x16 o[4];
    #pragma unroll
    for (int i = 0; i < 16; ++i) { o[0][i]=0.f; o[1][i]=0.f; o[2][i]=0.f; o[3][i]=0.f; }
    u32x4 pa0{0,0,0,0}, pa1{0,0,0,0}, pa2{0,0,0,0}, pa3{0,0,0,0};
    float m_run = -3.0e38f, l_run = 0.f;

    const int nt = q0b / KVBLK + 4;

    // ---- PV for the PREVIOUS tile, V read from the other buffer ----
    auto pv_block = [&](int buf) {
        const uint32_t vb = lds_off(&v_lds[buf][0]) + (uint32_t)((lane & 15) * 8)
                          + (uint32_t)(((lane >> 4) & 1) * 144) + (uint32_t)(hi * 2304);
        u32x2 a0,a1,a2,a3,a4,a5,a6,a7, b0,b1,b2,b3,b4,b5,b6,b7;
        TRSET(a0,a1,a2,a3,a4,a5,a6,a7, vb);
        TRSET(b0,b1,b2,b3,b4,b5,b6,b7, vb + 288);
        asm volatile("s_waitcnt lgkmcnt(8)");
        __builtin_amdgcn_sched_barrier(0);
        __builtin_amdgcn_s_setprio(1);
        MFMA4(0, a0,a1,a2,a3,a4,a5,a6,a7);
        __builtin_amdgcn_s_setprio(0);
        TRSET(a0,a1,a2,a3,a4,a5,a6,a7, vb + 576);
        asm volatile("s_waitcnt lgkmcnt(8)");
        __builtin_amdgcn_sched_barrier(0);
        __builtin_amdgcn_s_setprio(1);
        MFMA4(1, b0,b1,b2,b3,b4,b5,b6,b7);
        __builtin_amdgcn_s_setprio(0);
        TRSET(b0,b1,b2,b3,b4,b5,b6,b7, vb + 864);
        asm volatile("s_waitcnt lgkmcnt(8)");
        __builtin_amdgcn_sched_barrier(0);
        __builtin_amdgcn_s_setprio(1);
        MFMA4(2, a0,a1,a2,a3,a4,a5,a6,a7);
        __builtin_amdgcn_s_setprio(0);
        asm volatile("s_waitcnt lgkmcnt(0)");
        __builtin_amdgcn_sched_barrier(0);
        __builtin_amdgcn_s_setprio(1);
        MFMA4(3, b0,b1,b2,b3,b4,b5,b6,b7);
        __builtin_amdgcn_s_setprio(0);
    };

    // ---- prologue: tile 0 staged into buf0 ----
    StageRegs SR;
    stage_load(SR, 0);
    stage_write(SR, 0);

    bool act_prev = false;
    for (int t = 0; t < nt; ++t) {
        const int cur = t & 1;
        __syncthreads();                          // buf[cur] = tile t ready; buf[cur^1] = tile t-1 still live

        if (act_prev) pv_block(cur ^ 1);          // PV(t-1): register-state P x LDS V(t-1)

        const int kvb = t * KVBLK;
        const bool act = (kvb <= q0w + 31);
        f32x16 s0, s1;
        if (act) {
            // ---- QK^T (swapped): lane = q column, regs = kv rows ----
            const char* kbp = (const char*)&k_lds[cur][0];
            const uint32_t kxr = (uint32_t)((qcol & 15) << 4);
            #pragma unroll
            for (int i = 0; i < 16; ++i) { s0[i] = 0.f; s1[i] = 0.f; }
            __builtin_amdgcn_s_setprio(1);
            #pragma unroll
            for (int ch = 0; ch < 8; ++ch) {
                const uint32_t off = (uint32_t)(qcol * 256 + ((ch * 32 + hi * 16) ^ kxr));
                bf16x8 k0 = *reinterpret_cast<const bf16x8*>(kbp + off);
                bf16x8 k1 = *reinterpret_cast<const bf16x8*>(kbp + off + 8192);
                s0 = __builtin_amdgcn_mfma_f32_32x32x16_bf16(k0, aq[ch], s0, 0, 0, 0);
                s1 = __builtin_amdgcn_mfma_f32_32x32x16_bf16(k1, aq[ch], s1, 0, 0, 0);
            }
            __builtin_amdgcn_s_setprio(0);
        }

        if (t + 1 < nt) stage_load(SR, t + 1);    // VMEM issue, consumed after barrier2

        if (act) {
            // ---- causal mask ----
            if (kvb + KVBLK - 1 > q0w) {
                #pragma unroll
                for (int r = 0; r < 16; ++r) {
                    const int kv0 = kvb + (r & 3) + 8 * (r >> 2) + 4 * hi;
                    if (kv0 > qg)      s0[r] = -1.0e30f;
                    if (kv0 + 32 > qg) s1[r] = -1.0e30f;
                }
            }
            // ---- row max: in-lane + one cross ----
            float pm = s0[0];
            #pragma unroll
            for (int r = 1; r < 16; ++r) pm = fmaxf(pm, s0[r]);
            #pragma unroll
            for (int r = 0; r < 16; ++r) pm = fmaxf(pm, s1[r]);
            pm = fmaxf(pm, __shfl_xor(pm, 32));
            // ---- defer-max rescale (cold path) ----
            if (__any(pm - m_run > 8.0f)) {
                const float mn = fmaxf(m_run, pm);
                const float sc2 = __expf(m_run - mn);
                m_run = mn;
                l_run *= sc2;
                #pragma unroll
                for (int r = 0; r < 16; ++r) {
                    const float scr = __shfl(sc2, (r & 3) + 8 * (r >> 2) + 4 * hi);
                    o[0][r] *= scr; o[1][r] *= scr; o[2][r] *= scr; o[3][r] *= scr;
                }
            }
            // ---- P = exp(S - m), l rowsum in-lane ----
            #pragma unroll
            for (int r = 0; r < 16; ++r) s0[r] = __expf(s0[r] - m_run);
            #pragma unroll
            for (int r = 0; r < 16; ++r) s1[r] = __expf(s1[r] - m_run);
            float rs = 0.f;
            #pragma unroll
            for (int r = 0; r < 16; ++r) rs += s0[r] + s1[r];
            rs += __shfl_xor(rs, 32);
            l_run += rs;
            // ---- pack P -> bf16 A-fragments via permlane32_swap ----
            uint32_t w00 = pk2(s0[0],  s0[1]),  w01 = pk2(s0[2],  s0[3]);
            uint32_t w02 = pk2(s0[4],  s0[5]),  w03 = pk2(s0[6],  s0[7]);
            asm("v_permlane32_swap_b32 %0, %1" : "+v"(w00), "+v"(w02));
            asm("v_permlane32_swap_b32 %0, %1" : "+v"(w01), "+v"(w03));
            pa0 = u32x4{w00, w01, w02, w03};
            uint32_t w10 = pk2(s0[8],  s0[9]),  w11 = pk2(s0[10], s0[11]);
            uint32_t w12 = pk2(s0[12], s0[13]), w13 = pk2(s0[14], s0[15]);
            asm("v_permlane32_swap_b32 %0, %1" : "+v"(w10), "+v"(w12));
            asm("v_permlane32_swap_b32 %0, %1" : "+v"(w11), "+v"(w13));
            pa1 = u32x4{w10, w11, w12, w13};
            uint32_t w20 = pk2(s1[0],  s1[1]),  w21 = pk2(s1[2],  s1[3]);
            uint32_t w22 = pk2(s1[4],  s1[5]),  w23 = pk2(s1[6],  s1[7]);
            asm("v_permlane32_swap_b32 %0, %1" : "+v"(w20), "+v"(w22));
            asm("v_permlane32_swap_b32 %0, %1" : "+v"(w21), "+v"(w23));
            pa2 = u32x4{w20, w21, w22, w23};
            uint32_t w30 = pk2(s1[8],  s1[9]),  w31 = pk2(s1[10], s1[11]);
            uint32_t w32 = pk2(s1[12], s1[13]), w33 = pk2(s1[14], s1[15]);
            asm("v_permlane32_swap_b32 %0, %1" : "+v"(w30), "+v"(w32));
            asm("v_permlane32_swap_b32 %0, %1" : "+v"(w31), "+v"(w33));
            pa3 = u32x4{w30, w31, w32, w33};
        }

        __syncthreads();                          // all reads of buf[cur^1] done
        if (t + 1 < nt) stage_write(SR, cur ^ 1); // tile t+1 -> buf[cur^1]
        act_prev = act;
    }

    if (act_prev) pv_block((nt - 1) & 1);         // final PV

    // ---- epilogue: O = o / l (l broadcast via shfl) ----
    #pragma unroll
    for (int r = 0; r < 16; ++r) {
        const int rr = (r & 3) + 8 * (r >> 2) + 4 * hi;
        const float iv = 1.0f / __shfl(l_run, rr);
        float* op = O + base + (size_t)(q0w + rr) * D_DIM + qcol;
        op[0]  = o[0][r] * iv;
        op[32] = o[1][r] * iv;
        op[64] = o[2][r] * iv;
        op[96] = o[3][r] * iv;
    }
}

extern "C" void kernel_launch(void* const* d_in, const int* in_sizes, int n_in,
                              void* d_out, int out_size, void* d_ws, size_t ws_size,
                              hipStream_t stream) {
    const float* Q = (const float*)d_in[0];
    const float* K = (const float*)d_in[1];
    const float* V = (const float*)d_in[2];
    float* O = (float*)d_out;
    const int bh = in_sizes[0] / (S_DIM * D_DIM);   // B*H = 64
    dim3 grid(bh * (S_DIM / QBLK));                 // 512 blocks
    attn_fwd<<<grid, 512, 0, stream>>>(Q, K, V, O);
}

// Round 9
// 284.853 us; speedup vs baseline: 3.3566x; 3.3566x over previous
//
#include <hip/hip_runtime.h>
#include <hip/hip_bf16.h>
#include <stdint.h>

#define S_DIM 2048
#define D_DIM 128
#define QBLK 256          // 8 waves x 32 q-rows
#define KVBLK 64

typedef __attribute__((ext_vector_type(8)))  __bf16 bf16x8;
typedef __attribute__((ext_vector_type(16))) float  f32x16;
typedef __attribute__((ext_vector_type(2)))  unsigned int u32x2;
typedef __attribute__((ext_vector_type(4)))  unsigned int u32x4;

__device__ __forceinline__ uint32_t lds_off(const void* p) {
    return (uint32_t)(uintptr_t)p;   // low 32 bits of LDS flat addr = byte offset
}
__device__ __forceinline__ uint32_t pk2(float lo, float hi) {
    unsigned short a = __builtin_bit_cast(unsigned short, (__bf16)lo);
    unsigned short b = __builtin_bit_cast(unsigned short, (__bf16)hi);
    return (uint32_t)a | ((uint32_t)b << 16);
}

struct StageRegs { float4 k0, k1, k2, k3, v0, v1, v2, v3; };

// V window layout: elem idx = 72*W + (d&15) + 16*(kv&3)  [144 B windows]
//   W = 2*(d>>5) + ((d>>4)&1) + 8*((kv>>2)&1) + 16*((kv>>3)&1) + 32*(kv>>4)
#define TRSET(p0,p1,p2,p3,p4,p5,p6,p7, A) \
  asm volatile("ds_read_b64_tr_b16 %0, %1"              : "=v"(p0) : "v"(A)); \
  asm volatile("ds_read_b64_tr_b16 %0, %1 offset:1152"  : "=v"(p1) : "v"(A)); \
  asm volatile("ds_read_b64_tr_b16 %0, %1 offset:4608"  : "=v"(p2) : "v"(A)); \
  asm volatile("ds_read_b64_tr_b16 %0, %1 offset:5760"  : "=v"(p3) : "v"(A)); \
  asm volatile("ds_read_b64_tr_b16 %0, %1 offset:9216"  : "=v"(p4) : "v"(A)); \
  asm volatile("ds_read_b64_tr_b16 %0, %1 offset:10368" : "=v"(p5) : "v"(A)); \
  asm volatile("ds_read_b64_tr_b16 %0, %1 offset:13824" : "=v"(p6) : "v"(A)); \
  asm volatile("ds_read_b64_tr_b16 %0, %1 offset:14976" : "=v"(p7) : "v"(A));

#define MFMA4(nb, q0,q1,q2,q3,q4,q5,q6,q7)                                          \
  { u32x4 bu0 = {q0[0], q0[1], q1[0], q1[1]};                                       \
    o[nb] = __builtin_amdgcn_mfma_f32_32x32x16_bf16(                                \
        __builtin_bit_cast(bf16x8, pa0), __builtin_bit_cast(bf16x8, bu0), o[nb],0,0,0); \
    u32x4 bu1 = {q2[0], q2[1], q3[0], q3[1]};                                       \
    o[nb] = __builtin_amdgcn_mfma_f32_32x32x16_bf16(                                \
        __builtin_bit_cast(bf16x8, pa1), __builtin_bit_cast(bf16x8, bu1), o[nb],0,0,0); \
    u32x4 bu2 = {q4[0], q4[1], q5[0], q5[1]};                                       \
    o[nb] = __builtin_amdgcn_mfma_f32_32x32x16_bf16(                                \
        __builtin_bit_cast(bf16x8, pa2), __builtin_bit_cast(bf16x8, bu2), o[nb],0,0,0); \
    u32x4 bu3 = {q6[0], q6[1], q7[0], q7[1]};                                       \
    o[nb] = __builtin_amdgcn_mfma_f32_32x32x16_bf16(                                \
        __builtin_bit_cast(bf16x8, pa3), __builtin_bit_cast(bf16x8, bu3), o[nb],0,0,0); }

__global__ __launch_bounds__(512, 2)
void attn_fwd(const float* __restrict__ Q, const float* __restrict__ K,
              const float* __restrict__ V, float* __restrict__ O) {
    __shared__ __bf16 k_lds[2][KVBLK * D_DIM];      // row-major, byte ^= ((row&15)<<4)
    __shared__ __align__(16) char v_lds[2][18432];  // 128 windows x 144 B

    const int tid  = threadIdx.x;
    const int lane = tid & 63;
    const int wv   = tid >> 6;
    const int hi   = lane >> 5;
    const int qcol = lane & 31;

    // ---- block mapping: XCD-pinned by bh, makespan-paired jb ----
    const int bid  = (int)blockIdx.x;            // 0..511
    const int half = bid >> 8;
    const int idx  = bid & 255;
    const int xcd  = idx & 7;
    const int sub  = idx >> 3;
    const int bhg  = sub & 7;
    const int pp   = sub >> 3;
    const int jb   = half ? pp : 7 - pp;         // long blocks dispatch first
    const int bh   = bhg * 8 + xcd;
    const int q0b  = jb * QBLK;
    const int q0w  = q0b + wv * 32;
    const int qg   = q0w + qcol;

    const size_t base = (size_t)bh * S_DIM * D_DIM;
    const float* Qb = Q + base;
    const float* Kb = K + base;
    const float* Vb = V + base;

    // ---- staging: thread -> rows (sr, sr+32), 16B-chunk sc ----
    const int sr = tid >> 4;    // 0..31
    const int sc = tid & 15;    // 0..15
    const float* kg = Kb + (size_t)sr * D_DIM + sc * 8;
    const float* vg = Vb + (size_t)sr * D_DIM + sc * 8;
    const uint32_t kx    = (uint32_t)((sr & 15) << 4);
    const uint32_t koffA = (uint32_t)(sr * 256 + ((sc * 16) ^ kx));
    const uint32_t koffB = (uint32_t)((sr + 32) * 256 + ((sc * 16) ^ kx));
    const uint32_t voffA = (uint32_t)(144 * (2*(sc>>2) + ((sc>>1)&1) + 8*((sr>>2)&1)
                           + 16*((sr>>3)&1) + 32*(sr>>4)) + 16*(sc&1) + 32*(sr&3));
    const uint32_t voffB = voffA + 9216;         // rows +32 -> W += 64

    auto stage_load = [&](StageRegs& R, int t) {
        const size_t off = (size_t)t * KVBLK * D_DIM;
        R.k0 = *reinterpret_cast<const float4*>(kg + off);
        R.k1 = *reinterpret_cast<const float4*>(kg + off + 4);
        R.k2 = *reinterpret_cast<const float4*>(kg + off + 32 * D_DIM);
        R.k3 = *reinterpret_cast<const float4*>(kg + off + 32 * D_DIM + 4);
        R.v0 = *reinterpret_cast<const float4*>(vg + off);
        R.v1 = *reinterpret_cast<const float4*>(vg + off + 4);
        R.v2 = *reinterpret_cast<const float4*>(vg + off + 32 * D_DIM);
        R.v3 = *reinterpret_cast<const float4*>(vg + off + 32 * D_DIM + 4);
    };
    auto cvt8 = [](const float4& a, const float4& b) {
        bf16x8 r;
        r[0]=(__bf16)a.x; r[1]=(__bf16)a.y; r[2]=(__bf16)a.z; r[3]=(__bf16)a.w;
        r[4]=(__bf16)b.x; r[5]=(__bf16)b.y; r[6]=(__bf16)b.z; r[7]=(__bf16)b.w;
        return r;
    };
    auto stage_write = [&](const StageRegs& R, int buf) {
        char* kp = (char*)&k_lds[buf][0];
        *reinterpret_cast<bf16x8*>(kp + koffA) = cvt8(R.k0, R.k1);
        *reinterpret_cast<bf16x8*>(kp + koffB) = cvt8(R.k2, R.k3);
        char* vp = (char*)&v_lds[buf][0];
        *reinterpret_cast<bf16x8*>(vp + voffA) = cvt8(R.v0, R.v1);
        *reinterpret_cast<bf16x8*>(vp + voffB) = cvt8(R.v2, R.v3);
    };

    // ---- Q B-fragments (scale folded) ----
    const float qs = 0.08838834764831845f;
    bf16x8 aq[8];
    #pragma unroll
    for (int ch = 0; ch < 8; ++ch) {
        const float* qp = Qb + (size_t)qg * D_DIM + ch * 16 + hi * 8;
        float4 x = *reinterpret_cast<const float4*>(qp);
        float4 y = *reinterpret_cast<const float4*>(qp + 4);
        bf16x8 r;
        r[0]=(__bf16)(x.x*qs); r[1]=(__bf16)(x.y*qs); r[2]=(__bf16)(x.z*qs); r[3]=(__bf16)(x.w*qs);
        r[4]=(__bf16)(y.x*qs); r[5]=(__bf16)(y.y*qs); r[6]=(__bf16)(y.z*qs); r[7]=(__bf16)(y.w*qs);
        aq[ch] = r;
    }

    f32x16 o[4];
    #pragma unroll
    for (int i = 0; i < 16; ++i) { o[0][i]=0.f; o[1][i]=0.f; o[2][i]=0.f; o[3][i]=0.f; }
    u32x4 pa0{0,0,0,0}, pa1{0,0,0,0}, pa2{0,0,0,0}, pa3{0,0,0,0};
    float m_run = -3.0e38f, l_run = 0.f;

    const int nt = q0b / KVBLK + 4;

    // ---- PV for the PREVIOUS tile, V read from the other buffer ----
    auto pv_block = [&](int buf) {
        const uint32_t vb = lds_off(&v_lds[buf][0]) + (uint32_t)((lane & 15) * 8)
                          + (uint32_t)(((lane >> 4) & 1) * 144) + (uint32_t)(hi * 2304);
        u32x2 a0,a1,a2,a3,a4,a5,a6,a7, b0,b1,b2,b3,b4,b5,b6,b7;
        TRSET(a0,a1,a2,a3,a4,a5,a6,a7, vb);
        TRSET(b0,b1,b2,b3,b4,b5,b6,b7, vb + 288);
        asm volatile("s_waitcnt lgkmcnt(8)");
        __builtin_amdgcn_sched_barrier(0);
        __builtin_amdgcn_s_setprio(1);
        MFMA4(0, a0,a1,a2,a3,a4,a5,a6,a7);
        __builtin_amdgcn_s_setprio(0);
        TRSET(a0,a1,a2,a3,a4,a5,a6,a7, vb + 576);
        asm volatile("s_waitcnt lgkmcnt(8)");
        __builtin_amdgcn_sched_barrier(0);
        __builtin_amdgcn_s_setprio(1);
        MFMA4(1, b0,b1,b2,b3,b4,b5,b6,b7);
        __builtin_amdgcn_s_setprio(0);
        TRSET(b0,b1,b2,b3,b4,b5,b6,b7, vb + 864);
        asm volatile("s_waitcnt lgkmcnt(8)");
        __builtin_amdgcn_sched_barrier(0);
        __builtin_amdgcn_s_setprio(1);
        MFMA4(2, a0,a1,a2,a3,a4,a5,a6,a7);
        __builtin_amdgcn_s_setprio(0);
        asm volatile("s_waitcnt lgkmcnt(0)");
        __builtin_amdgcn_sched_barrier(0);
        __builtin_amdgcn_s_setprio(1);
        MFMA4(3, b0,b1,b2,b3,b4,b5,b6,b7);
        __builtin_amdgcn_s_setprio(0);
    };

    // ---- prologue: tile 0 staged into buf0 ----
    StageRegs SR;
    stage_load(SR, 0);
    stage_write(SR, 0);

    bool act_prev = false;
    for (int t = 0; t < nt; ++t) {
        const int cur = t & 1;
        __syncthreads();                          // buf[cur] = tile t ready; buf[cur^1] = tile t-1 still live

        if (act_prev) pv_block(cur ^ 1);          // PV(t-1): register-state P x LDS V(t-1)

        const int kvb = t * KVBLK;
        const bool act = (kvb <= q0w + 31);
        f32x16 s0, s1;
        if (act) {
            // ---- QK^T (swapped): lane = q column, regs = kv rows ----
            const char* kbp = (const char*)&k_lds[cur][0];
            const uint32_t kxr = (uint32_t)((qcol & 15) << 4);
            #pragma unroll
            for (int i = 0; i < 16; ++i) { s0[i] = 0.f; s1[i] = 0.f; }
            __builtin_amdgcn_s_setprio(1);
            #pragma unroll
            for (int ch = 0; ch < 8; ++ch) {
                const uint32_t off = (uint32_t)(qcol * 256 + ((ch * 32 + hi * 16) ^ kxr));
                bf16x8 k0 = *reinterpret_cast<const bf16x8*>(kbp + off);
                bf16x8 k1 = *reinterpret_cast<const bf16x8*>(kbp + off + 8192);
                s0 = __builtin_amdgcn_mfma_f32_32x32x16_bf16(k0, aq[ch], s0, 0, 0, 0);
                s1 = __builtin_amdgcn_mfma_f32_32x32x16_bf16(k1, aq[ch], s1, 0, 0, 0);
            }
            __builtin_amdgcn_s_setprio(0);
        }

        if (t + 1 < nt) stage_load(SR, t + 1);    // VMEM issue, consumed after barrier2

        if (act) {
            // ---- causal mask ----
            if (kvb + KVBLK - 1 > q0w) {
                #pragma unroll
                for (int r = 0; r < 16; ++r) {
                    const int kv0 = kvb + (r & 3) + 8 * (r >> 2) + 4 * hi;
                    if (kv0 > qg)      s0[r] = -1.0e30f;
                    if (kv0 + 32 > qg) s1[r] = -1.0e30f;
                }
            }
            // ---- row max: in-lane + one cross ----
            float pm = s0[0];
            #pragma unroll
            for (int r = 1; r < 16; ++r) pm = fmaxf(pm, s0[r]);
            #pragma unroll
            for (int r = 0; r < 16; ++r) pm = fmaxf(pm, s1[r]);
            pm = fmaxf(pm, __shfl_xor(pm, 32));
            // ---- defer-max rescale (cold path) ----
            if (__any(pm - m_run > 8.0f)) {
                const float mn = fmaxf(m_run, pm);
                const float sc2 = __expf(m_run - mn);
                m_run = mn;
                l_run *= sc2;
                #pragma unroll
                for (int r = 0; r < 16; ++r) {
                    const float scr = __shfl(sc2, (r & 3) + 8 * (r >> 2) + 4 * hi);
                    o[0][r] *= scr; o[1][r] *= scr; o[2][r] *= scr; o[3][r] *= scr;
                }
            }
            // ---- P = exp(S - m), l rowsum in-lane ----
            #pragma unroll
            for (int r = 0; r < 16; ++r) s0[r] = __expf(s0[r] - m_run);
            #pragma unroll
            for (int r = 0; r < 16; ++r) s1[r] = __expf(s1[r] - m_run);
            float rs = 0.f;
            #pragma unroll
            for (int r = 0; r < 16; ++r) rs += s0[r] + s1[r];
            rs += __shfl_xor(rs, 32);
            l_run += rs;
            // ---- pack P -> bf16 A-fragments via permlane32_swap ----
            uint32_t w00 = pk2(s0[0],  s0[1]),  w01 = pk2(s0[2],  s0[3]);
            uint32_t w02 = pk2(s0[4],  s0[5]),  w03 = pk2(s0[6],  s0[7]);
            asm("v_permlane32_swap_b32 %0, %1" : "+v"(w00), "+v"(w02));
            asm("v_permlane32_swap_b32 %0, %1" : "+v"(w01), "+v"(w03));
            pa0 = u32x4{w00, w01, w02, w03};
            uint32_t w10 = pk2(s0[8],  s0[9]),  w11 = pk2(s0[10], s0[11]);
            uint32_t w12 = pk2(s0[12], s0[13]), w13 = pk2(s0[14], s0[15]);
            asm("v_permlane32_swap_b32 %0, %1" : "+v"(w10), "+v"(w12));
            asm("v_permlane32_swap_b32 %0, %1" : "+v"(w11), "+v"(w13));
            pa1 = u32x4{w10, w11, w12, w13};
            uint32_t w20 = pk2(s1[0],  s1[1]),  w21 = pk2(s1[2],  s1[3]);
            uint32_t w22 = pk2(s1[4],  s1[5]),  w23 = pk2(s1[6],  s1[7]);
            asm("v_permlane32_swap_b32 %0, %1" : "+v"(w20), "+v"(w22));
            asm("v_permlane32_swap_b32 %0, %1" : "+v"(w21), "+v"(w23));
            pa2 = u32x4{w20, w21, w22, w23};
            uint32_t w30 = pk2(s1[8],  s1[9]),  w31 = pk2(s1[10], s1[11]);
            uint32_t w32 = pk2(s1[12], s1[13]), w33 = pk2(s1[14], s1[15]);
            asm("v_permlane32_swap_b32 %0, %1" : "+v"(w30), "+v"(w32));
            asm("v_permlane32_swap_b32 %0, %1" : "+v"(w31), "+v"(w33));
            pa3 = u32x4{w30, w31, w32, w33};
        }

        __syncthreads();                          // all reads of buf[cur^1] done
        if (t + 1 < nt) stage_write(SR, cur ^ 1); // tile t+1 -> buf[cur^1]
        act_prev = act;
    }

    if (act_prev) pv_block((nt - 1) & 1);         // final PV

    // ---- epilogue: O = o / l (l broadcast via shfl) ----
    #pragma unroll
    for (int r = 0; r < 16; ++r) {
        const int rr = (r & 3) + 8 * (r >> 2) + 4 * hi;
        const float iv = 1.0f / __shfl(l_run, rr);
        float* op = O + base + (size_t)(q0w + rr) * D_DIM + qcol;
        op[0]  = o[0][r] * iv;
        op[32] = o[1][r] * iv;
        op[64] = o[2][r] * iv;
        op[96] = o[3][r] * iv;
    }
}

extern "C" void kernel_launch(void* const* d_in, const int* in_sizes, int n_in,
                              void* d_out, int out_size, void* d_ws, size_t ws_size,
                              hipStream_t stream) {
    const float* Q = (const float*)d_in[0];
    const float* K = (const float*)d_in[1];
    const float* V = (const float*)d_in[2];
    float* O = (float*)d_out;
    const int bh = in_sizes[0] / (S_DIM * D_DIM);   // B*H = 64
    dim3 grid(bh * (S_DIM / QBLK));                 // 512 blocks
    attn_fwd<<<grid, 512, 0, stream>>>(Q, K, V, O);
}